// Round 8
// baseline (93.331 us; speedup 1.0000x reference)
//
#include <hip/hip_runtime.h>
#include <stdint.h>

#define NQ 12
#define DIM 4096
#define NLAYERS 6
#define TPB 512
#define NL 8           // amps per thread (3 local bits)

typedef float v2f __attribute__((ext_vector_type(2)));

// ---------------------------------------------------------------------------
// R8: R7 structure (TPB=512, 8 amps/thread, 4 waves/SIMD, 23 GF(2) gather
// passes with compile-time conflict-free LDS layouts), but register gates
// rewritten with __builtin_elementwise_fma on v2f so ISel emits
// v_pk_fma_f32 (packed fp32) with op_sel/neg folding of the J-swizzle —
// targeting ~2x fewer VALU instructions per gate.
// k bits: 0..2 register-local, 3..8 lane (tid 0..5), 9..11 block-thread.
// Per layer: rebase (folds CNOT A_{l-1}) + S1 + S2 + S3 window swaps, each
// followed by 3 register gates. Layer 5's CNOT folds into epilogue rows.
// ---------------------------------------------------------------------------
struct Pass_t {
    uint32_t WT[9];    // Lambda columns for thread bits (k bits 3..11)
    uint32_t WL[NL];   // Lambda image of local octet l
    uint32_t RT[9];    // (Lambda o M) columns for thread bits
    uint32_t RL[NL];   // (Lambda o M) image of local octet l
};
struct CK_t {
    Pass_t PS1, PS2, PS3;   // fixed window swaps
    Pass_t P1[NLAYERS];     // per-layer rebase (index 1..5 used)
    uint32_t frow[NQ];      // epilogue sign rows
};

constexpr uint32_t S1f(uint32_t k){ return ((k&7u)<<3) | ((k>>3)&7u) | (k & 0xFC0u); }
constexpr uint32_t S2f(uint32_t k){ return ((k&7u)<<6) | (k & 0x38u) | ((k>>6)&7u) | (k & 0xE00u); }
constexpr uint32_t S3f(uint32_t k){ return ((k&7u)<<9) | (k & 0x1F8u) | ((k>>9)&7u); }

constexpr uint32_t ech_reduce(const uint32_t* v, int n, uint32_t x){
    bool ch = true;
    while (ch) {
        ch = false;
        for (int i = 0; i < n; i++)
            if (v[i] && (x ^ v[i]) < x) { x ^= v[i]; ch = true; }
    }
    return x;
}

constexpr Pass_t build_pass(const uint32_t* Mc) {
    Pass_t P{};
    uint32_t rows[12]{}; int nr = 0;
    {   // greedy bank rows: rank 4 on {e3..e6} and on {Mc[3]..Mc[6]}
        uint32_t e1[4]{}, e2[4]{}; int n1 = 0, n2 = 0;
        for (int step = 0; step < 4; step++) {
            bool found = false;
            for (int pc = 1; pc <= 3 && !found; pc++) {
                for (int a = 0; a < 12 && !found; a++)
                for (int b = (pc >= 2 ? a + 1 : 12); (pc >= 2 ? b < 12 : b == 12) && !found; b++)
                for (int c = (pc == 3 ? b + 1 : 12); (pc == 3 ? c < 12 : c == 12) && !found; c++) {
                    uint32_t m = (1u << a);
                    if (pc >= 2) m |= (1u << b);
                    if (pc == 3) m |= (1u << c);
                    uint32_t v1 = (m >> 3) & 15u;
                    uint32_t v2 = 0;
                    for (int j = 0; j < 4; j++)
                        v2 |= (uint32_t)(__builtin_popcount(m & Mc[3 + j]) & 1) << j;
                    uint32_t r1 = ech_reduce(e1, n1, v1);
                    uint32_t r2 = ech_reduce(e2, n2, v2);
                    if (r1 && r2) {
                        rows[nr++] = m; e1[n1++] = r1; e2[n2++] = r2; found = true;
                    }
                }
            }
            if (!found) { rows[nr] = 1u << (3 + nr); nr++; }
        }
    }
    {   // complete to an invertible 12x12
        uint32_t ef[12]{}; int nf = 0;
        for (int i = 0; i < nr; i++) {
            uint32_t r = ech_reduce(ef, nf, rows[i]);
            if (r) ef[nf++] = r;
        }
        for (uint32_t m = 1; m < 4096u && nr < 12; m++) {
            uint32_t r = ech_reduce(ef, nf, m);
            if (r) { rows[nr++] = m; ef[nf++] = r; }
        }
    }
    uint32_t col[12]{}, rc[12]{};
    for (int j = 0; j < 12; j++) {
        uint32_t c = 0;
        for (int i = 0; i < 12; i++) c |= (uint32_t)((rows[i] >> j) & 1u) << i;
        col[j] = c;
    }
    for (int j = 0; j < 12; j++) {
        uint32_t a = 0, mc = Mc[j];
        for (int q = 0; q < 12; q++) if ((mc >> q) & 1u) a ^= col[q];
        rc[j] = a;
    }
    for (int j = 0; j < 9; j++) { P.WT[j] = col[3 + j]; P.RT[j] = rc[3 + j]; }
    for (int l = 0; l < NL; l++) {
        uint32_t aw = 0, ar = 0;
        for (int q = 0; q < 3; q++) if ((l >> q) & 1) { aw ^= col[q]; ar ^= rc[q]; }
        P.WL[l] = aw; P.RL[l] = ar;
    }
    return P;
}

constexpr CK_t build_ck() {
    CK_t ck{};
    uint32_t Acols[NLAYERS][NQ]{}, Aicol5[NQ]{};
    for (int l = 0; l < NLAYERS; l++) {
        int r = l % (NQ - 1) + 1;
        for (int q = 0; q < NQ; q++) {
            uint32_t v = 1u << q;
            for (int w = NQ - 1; w >= 0; w--) {            // A = T0∘T1∘...∘T11
                int pc = NQ - 1 - w, pt = NQ - 1 - ((w + r) % NQ);
                v ^= ((v >> pc) & 1u) << pt;
            }
            Acols[l][q] = v;
            if (l == NLAYERS - 1) {
                uint32_t u = 1u << q;
                for (int w = 0; w < NQ; w++) {             // A^-1
                    int pc = NQ - 1 - w, pt = NQ - 1 - ((w + r) % NQ);
                    u ^= ((u >> pc) & 1u) << pt;
                }
                Aicol5[q] = u;
            }
        }
    }
    uint32_t Mc[12]{};
    for (int j = 0; j < 12; j++) Mc[j] = S1f(1u << j);
    ck.PS1 = build_pass(Mc);
    for (int j = 0; j < 12; j++) Mc[j] = S2f(1u << j);
    ck.PS2 = build_pass(Mc);
    for (int j = 0; j < 12; j++) Mc[j] = S3f(1u << j);
    ck.PS3 = build_pass(Mc);
    for (int l = 1; l < NLAYERS; l++) {
        for (int j = 0; j < 12; j++) Mc[j] = S3f(S2f(S1f(Acols[l - 1][j])));
        ck.P1[l] = build_pass(Mc);
    }
    // epilogue: i(k) = A5^-1(pi'(k)), pi'(v) = S1(S2(S3(v)))
    uint32_t Mcol[NQ]{};
    for (int j = 0; j < NQ; j++) {
        uint32_t pj = S1f(S2f(S3f(1u << j)));
        uint32_t M = 0;
        for (int m = 0; m < NQ; m++) if ((pj >> m) & 1u) M ^= Aicol5[m];
        Mcol[j] = M;
    }
    for (int p = 0; p < NQ; p++) {
        uint32_t s = 0;
        for (int j = 0; j < NQ; j++) s |= ((Mcol[j] >> p) & 1u) << j;
        ck.frow[p] = s;
    }
    return ck;
}
constexpr CK_t CK = build_ck();

// KIND: 1 = layer rebase, 2 = S1, 3 = S2, 4 = S3. Double-buffered: 1 barrier.
template<int KIND, int L, int PAR>
__device__ __forceinline__ void do_pass(v2f (&Z)[NL], v2f* xb, int tid) {
    constexpr Pass_t P = (KIND == 1) ? CK.P1[L]
                       : (KIND == 2) ? CK.PS1
                       : (KIND == 3) ? CK.PS2 : CK.PS3;
    v2f* buf = xb + PAR * DIM;
    uint32_t comb = 0;
    #pragma unroll
    for (int j = 0; j < 9; j++) {
        uint32_t pk = P.WT[j] | (P.RT[j] << 16);
        comb ^= (uint32_t)(-(int)((tid >> j) & 1)) & pk;
    }
    uint32_t wbase = comb & 0xFFFu, rbase = comb >> 16;
    #pragma unroll
    for (int l = 0; l < NL; l++)
        buf[wbase ^ P.WL[l]] = Z[l];
    __syncthreads();
    #pragma unroll
    for (int l = 0; l < NL; l++)
        Z[l] = buf[rbase ^ P.RL[l]];
}

// rotation on wire W at register-local bit Q; m = (m00r, m00i, m01r, m01i),
// m10 = -m.z + i*m.w, m11 = m.x - i*m.y.  J(z) = (-z.y, z.x).
// __builtin_elementwise_fma on v2f -> v_pk_fma_f32; the J-swizzle and fneg
// fold into VOP3P op_sel / neg modifiers.
template<int L, int W, int Q>
__device__ __forceinline__ void reg_gate(v2f (&Z)[NL], const float4* smat) {
    float4 m = smat[L * NQ + W];
    v2f mx = {m.x, m.x}, my = {m.y, m.y}, mz = {m.z, m.z}, mw = {m.w, m.w};
    #pragma unroll
    for (int l = 0; l < NL; l++) {
        if (l & (1 << Q)) continue;
        int l2 = l | (1 << Q);
        v2f z0 = Z[l], z1 = Z[l2];
        v2f j0 = { -z0.y, z0.x };
        v2f j1 = { -z1.y, z1.x };
        Z[l]  = __builtin_elementwise_fma(mx, z0,
                __builtin_elementwise_fma(my, j0,
                __builtin_elementwise_fma(mz, z1, mw * j1)));
        Z[l2] = __builtin_elementwise_fma(mx, z1,
                __builtin_elementwise_fma(my, -j1,
                __builtin_elementwise_fma(mz, -z0, mw * j0)));
    }
}

template<int L>
__device__ __forceinline__ void do_layer(v2f (&Z)[NL], const float4* smat,
                                         v2f* xb, int tid) {
    // pass parities: rebase=1, S1=0, S2=1, S3=0 (alternates globally)
    if constexpr (L > 0)
        do_pass<1, L, 1>(Z, xb, tid);
    reg_gate<L, 11, 0>(Z, smat);
    reg_gate<L, 10, 1>(Z, smat);
    reg_gate<L,  9, 2>(Z, smat);
    do_pass<2, L, 0>(Z, xb, tid);
    reg_gate<L, 8, 0>(Z, smat);
    reg_gate<L, 7, 1>(Z, smat);
    reg_gate<L, 6, 2>(Z, smat);
    do_pass<3, L, 1>(Z, xb, tid);
    reg_gate<L, 5, 0>(Z, smat);
    reg_gate<L, 4, 1>(Z, smat);
    reg_gate<L, 3, 2>(Z, smat);
    do_pass<4, L, 0>(Z, xb, tid);
    reg_gate<L, 2, 0>(Z, smat);
    reg_gate<L, 1, 1>(Z, smat);
    reg_gate<L, 0, 2>(Z, smat);
}

__global__ __launch_bounds__(TPB) void qsim_kernel(
    const float* __restrict__ x,        // [512,12]
    const float* __restrict__ weights,  // [6,12,3]
    const float* __restrict__ Wp,       // [12]
    const float* __restrict__ bptr,     // [1]
    float* __restrict__ out)            // [512]
{
    __shared__ v2f    xb[2 * DIM];      // 64 KB double-buffered exchange
    __shared__ float4 smat[NLAYERS * NQ];
    __shared__ float  scs[NQ], sss[NQ];
    __shared__ float  red[8];

    const int tid = threadIdx.x;
    const int b   = blockIdx.x;

    if (tid < NQ) {
        float s_, c_;
        sincosf(0.5f * x[b * NQ + tid], &s_, &c_);
        scs[tid] = c_; sss[tid] = s_;
    }
    if (tid < NLAYERS * NQ) {
        float phi   = weights[tid * 3 + 0];
        float theta = weights[tid * 3 + 1];
        float omega = weights[tid * 3 + 2];
        float st, ct; sincosf(0.5f * theta, &st, &ct);
        float sp, cp; sincosf(0.5f * (phi + omega), &sp, &cp);
        float sm, cm; sincosf(0.5f * (phi - omega), &sm, &cm);
        smat[tid] = make_float4(cp * ct, -sp * ct, -cm * st, -sm * st);
    }
    __syncthreads();

    // product-state init, identity basis: k = (tid<<3)|l, bit p <-> wire 11-p
    float base = 1.0f;
    #pragma unroll
    for (int j = 0; j < 9; j++) {
        int w = 8 - j;                  // wire of k bit 3+j
        base *= ((tid >> j) & 1) ? sss[w] : scs[w];
    }
    v2f Z[NL];
    #pragma unroll
    for (int l = 0; l < NL; l++) {
        float a = base;
        #pragma unroll
        for (int p = 0; p < 3; p++) {
            int w = NQ - 1 - p;
            a *= ((l >> p) & 1) ? sss[w] : scs[w];
        }
        Z[l].x = a; Z[l].y = 0.0f;
    }

    do_layer<0>(Z, smat, xb, tid);
    do_layer<1>(Z, smat, xb, tid);
    do_layer<2>(Z, smat, xb, tid);
    do_layer<3>(Z, smat, xb, tid);
    do_layer<4>(Z, smat, xb, tid);
    do_layer<5>(Z, smat, xb, tid);

    // expectation: coef = b + sum_p W[11-p]*(1-2*bit_p(i(k)))
    const float bv = bptr[0];
    float wb[NQ];
    #pragma unroll
    for (int p = 0; p < NQ; p++) {
        uint32_t row = CK.frow[p];
        int tp = __popc(tid & (int)(row >> 3)) & 1;
        float Wv = Wp[NQ - 1 - p];
        wb[p] = tp ? -Wv : Wv;
    }
    float acc = 0.0f;
    #pragma unroll
    for (int l = 0; l < NL; l++) {
        float coef = bv;
        #pragma unroll
        for (int p = 0; p < NQ; p++)
            coef += (__popc(l & (int)(CK.frow[p] & 7u)) & 1) ? -wb[p] : wb[p];
        acc += (Z[l].x * Z[l].x + Z[l].y * Z[l].y) * coef;
    }
    #pragma unroll
    for (int off = 32; off > 0; off >>= 1)
        acc += __shfl_down(acc, off, 64);
    if ((tid & 63) == 0) red[tid >> 6] = acc;
    __syncthreads();
    if (tid == 0) {
        float s = 0.0f;
        #pragma unroll
        for (int wv = 0; wv < TPB / 64; wv++) s += red[wv];
        out[b] = s;
    }
}

extern "C" void kernel_launch(void* const* d_in, const int* in_sizes, int n_in,
                              void* d_out, int out_size, void* d_ws, size_t ws_size,
                              hipStream_t stream) {
    const float* x       = (const float*)d_in[0];
    const float* weights = (const float*)d_in[1];
    const float* W       = (const float*)d_in[2];
    const float* bptr    = (const float*)d_in[3];
    qsim_kernel<<<512, TPB, 0, stream>>>(x, weights, W, bptr, (float*)d_out);
}

// Round 9
// 91.800 us; speedup vs baseline: 1.0167x; 1.0167x over previous
//
#include <hip/hip_runtime.h>
#include <stdint.h>

#define NQ 12
#define DIM 4096
#define NLAYERS 6
#define TPB 256

typedef float v2f __attribute__((ext_vector_type(2)));

// ---------------------------------------------------------------------------
// R9: structural packed-fp32. 16 amps/thread; local k bits 0..3 where bit 3
// is a PACK bit (never gated): state = v2f PRE[8]/PIM[8], halves = bit3=0/1.
// All 72 rotations act on local bits 0..2 => pure element-wise v_pk_fma_f32
// with scalar broadcasts (no swizzles). Pass/window algebra = R7 verbatim
// (S1/S2/S3 swaps + per-layer rebase folding CNOT A_{l-1}; layer-5 CNOT in
// epilogue rows). LDS per pass: RE plane [0,4096) + IM plane [4096,8192).
// Layout Lambda per pass: rows r0..r11, r0 = e3 (so Lambda(e3)=e0: packed
// pairs are contiguous b64 writes, natural .x/.y orientation), rows 1..4
// greedy full-rank on write span (k4..7 -> slot1..4) and read span
// ((Lambda o M) on k4..8 -> slot0..4, or k4..7 -> slot1..4 for passes fixing
// e3 which read b64). Residual read aliasing is <=2-way (free, m136).
// ---------------------------------------------------------------------------
struct Pass_t {
    uint32_t WT[8];    // Lambda cols, k bits 4..11 (thread bits)
    uint32_t WL[8];    // Lambda(j), j = local bits 0..2 (even slots)
    uint32_t RT[8];    // (Lambda o M) cols, k bits 4..11
    uint32_t RL[16];   // (Lambda o M)(l), l = local bits 0..3
    bool r64;          // M fixes e3 => b64 reads
};
struct CK_t {
    Pass_t PS1, PS2, PS3;   // fixed window swaps
    Pass_t P1[NLAYERS];     // per-layer rebase (index 1..5 used)
    uint32_t frow[NQ];      // epilogue sign rows
};

constexpr uint32_t S1f(uint32_t k){ return ((k&7u)<<3) | ((k>>3)&7u) | (k & 0xFC0u); }
constexpr uint32_t S2f(uint32_t k){ return ((k&7u)<<6) | (k & 0x38u) | ((k>>6)&7u) | (k & 0xE00u); }
constexpr uint32_t S3f(uint32_t k){ return ((k&7u)<<9) | (k & 0x1F8u) | ((k>>9)&7u); }

constexpr uint32_t ech_reduce(const uint32_t* v, int n, uint32_t x){
    bool ch = true;
    while (ch) {
        ch = false;
        for (int i = 0; i < n; i++)
            if (v[i] && (x ^ v[i]) < x) { x ^= v[i]; ch = true; }
    }
    return x;
}

constexpr Pass_t build_pass(const uint32_t* Mc) {
    Pass_t P{};
    bool r64 = (Mc[3] == 8u);
    for (int j = 0; j < 12; j++) if (j != 3 && (Mc[j] & 8u)) r64 = false;
    P.r64 = r64;

    uint32_t rows[12]{};
    rows[0] = 8u;                       // r0 = e3
    int nr = 1;
    uint32_t full[12]{}; int nf = 0; full[nf++] = 8u;
    uint32_t We[4]{};  int nw = 0;
    uint32_t Re[5]{};  int nre = 0;
    const int rpn = r64 ? 4 : 5;        // read-span width
    if (!r64) {                          // row0's read projection (b32 case)
        uint32_t p0 = 0;
        for (int j = 0; j < rpn; j++)
            p0 |= (uint32_t)(__builtin_popcount(8u & Mc[4 + j]) & 1) << j;
        uint32_t r = ech_reduce(Re, nre, p0);
        if (r) Re[nre++] = r;
    }
    for (int slot = 0; slot < 4; slot++) {
        uint32_t chosen = 0;
        for (int relax = 0; relax < 3 && !chosen; relax++) {
            for (uint32_t m = 1; m < 4096u && !chosen; m++) {
                if (m & 8u) continue;
                uint32_t wp = (m >> 4) & 15u;
                uint32_t wr = ech_reduce(We, nw, wp);
                if (relax < 2 && !wr) continue;
                uint32_t rp = 0;
                for (int j = 0; j < rpn; j++)
                    rp |= (uint32_t)(__builtin_popcount(m & Mc[4 + j]) & 1) << j;
                uint32_t rr = ech_reduce(Re, nre, rp);
                if (relax < 1 && !rr) continue;
                uint32_t fr = ech_reduce(full, nf, m);
                if (!fr) continue;
                chosen = m; full[nf++] = fr;
                if (wr && nw < 4) We[nw++] = wr;
                if (rr && nre < 5) Re[nre++] = rr;
            }
        }
        rows[nr++] = chosen;
    }
    for (int slot = 5; slot < 12; slot++) {
        for (uint32_t m = 1; m < 4096u; m++) {
            if (m & 8u) continue;
            uint32_t fr = ech_reduce(full, nf, m);
            if (fr) { rows[nr++] = m; full[nf++] = fr; break; }
        }
    }
    uint32_t col[12]{}, lmc[12]{};
    for (int j = 0; j < 12; j++) {
        uint32_t c = 0;
        for (int i = 0; i < 12; i++) c |= (uint32_t)((rows[i] >> j) & 1u) << i;
        col[j] = c;
    }
    for (int j = 0; j < 12; j++) {
        uint32_t a = 0, mc = Mc[j];
        for (int q = 0; q < 12; q++) if ((mc >> q) & 1u) a ^= col[q];
        lmc[j] = a;
    }
    for (int j = 0; j < 8; j++) { P.WT[j] = col[4 + j]; P.RT[j] = lmc[4 + j]; }
    for (int j = 0; j < 8; j++) {
        uint32_t a = 0;
        for (int q = 0; q < 3; q++) if ((j >> q) & 1) a ^= col[q];
        P.WL[j] = a;
    }
    for (int l = 0; l < 16; l++) {
        uint32_t a = 0;
        for (int q = 0; q < 4; q++) if ((l >> q) & 1) a ^= lmc[q];
        P.RL[l] = a;
    }
    return P;
}

constexpr CK_t build_ck() {
    CK_t ck{};
    uint32_t Acols[NLAYERS][NQ]{}, Aicol5[NQ]{};
    for (int l = 0; l < NLAYERS; l++) {
        int r = l % (NQ - 1) + 1;
        for (int q = 0; q < NQ; q++) {
            uint32_t v = 1u << q;
            for (int w = NQ - 1; w >= 0; w--) {            // A = T0∘T1∘...∘T11
                int pc = NQ - 1 - w, pt = NQ - 1 - ((w + r) % NQ);
                v ^= ((v >> pc) & 1u) << pt;
            }
            Acols[l][q] = v;
            if (l == NLAYERS - 1) {
                uint32_t u = 1u << q;
                for (int w = 0; w < NQ; w++) {             // A^-1
                    int pc = NQ - 1 - w, pt = NQ - 1 - ((w + r) % NQ);
                    u ^= ((u >> pc) & 1u) << pt;
                }
                Aicol5[q] = u;
            }
        }
    }
    uint32_t Mc[12]{};
    for (int j = 0; j < 12; j++) Mc[j] = S1f(1u << j);
    ck.PS1 = build_pass(Mc);
    for (int j = 0; j < 12; j++) Mc[j] = S2f(1u << j);
    ck.PS2 = build_pass(Mc);
    for (int j = 0; j < 12; j++) Mc[j] = S3f(1u << j);
    ck.PS3 = build_pass(Mc);
    for (int l = 1; l < NLAYERS; l++) {
        for (int j = 0; j < 12; j++) Mc[j] = S3f(S2f(S1f(Acols[l - 1][j])));
        ck.P1[l] = build_pass(Mc);
    }
    uint32_t Mcol[NQ]{};
    for (int j = 0; j < NQ; j++) {
        uint32_t pj = S1f(S2f(S3f(1u << j)));
        uint32_t M = 0;
        for (int m = 0; m < NQ; m++) if ((pj >> m) & 1u) M ^= Aicol5[m];
        Mcol[j] = M;
    }
    for (int p = 0; p < NQ; p++) {
        uint32_t s = 0;
        for (int j = 0; j < NQ; j++) s |= ((Mcol[j] >> p) & 1u) << j;
        ck.frow[p] = s;
    }
    return ck;
}
constexpr CK_t CK = build_ck();

// KIND: 1 = layer rebase, 2 = S1, 3 = S2, 4 = S3. Double-buffered, 1 barrier.
template<int KIND, int L, int PAR>
__device__ __forceinline__ void do_pass(v2f (&PRE)[8], v2f (&PIM)[8],
                                        float* lds, int tid) {
    constexpr Pass_t P = (KIND == 1) ? CK.P1[L]
                       : (KIND == 2) ? CK.PS1
                       : (KIND == 3) ? CK.PS2 : CK.PS3;
    float* buf = lds + PAR * (2 * DIM);
    uint32_t comb = 0;
    #pragma unroll
    for (int j = 0; j < 8; j++) {
        uint32_t pk = P.WT[j] | (P.RT[j] << 16);
        comb ^= (uint32_t)(-(int)((tid >> j) & 1)) & pk;
    }
    uint32_t wb = comb & 0xFFFFu, rb = comb >> 16;
    v2f* bre = (v2f*)buf;
    v2f* bim = (v2f*)(buf + DIM);
    #pragma unroll
    for (int j = 0; j < 8; j++) {
        uint32_t s = (wb ^ P.WL[j]) >> 1;
        bre[s] = PRE[j];
        bim[s] = PIM[j];
    }
    __syncthreads();
    if constexpr (P.r64) {
        #pragma unroll
        for (int j = 0; j < 8; j++) {
            uint32_t s = (rb ^ P.RL[j]) >> 1;
            PRE[j] = bre[s];
            PIM[j] = bim[s];
        }
    } else {
        #pragma unroll
        for (int j = 0; j < 8; j++) {
            uint32_t s0 = rb ^ P.RL[j], s1 = rb ^ P.RL[j | 8];
            v2f re, im;
            re.x = buf[s0];        re.y = buf[s1];
            im.x = buf[DIM + s0];  im.y = buf[DIM + s1];
            PRE[j] = re;
            PIM[j] = im;
        }
    }
}

// rotation on wire W at local bit Q (0..2); m = (m00r,m00i,m01r,m01i);
// m10 = (-m.z, m.w), m11 = (m.x, -m.y). Element-wise on packed halves:
// pure v_pk_fma_f32 / v_pk_mul_f32, no swizzles.
template<int L, int W, int Q>
__device__ __forceinline__ void reg_gate(v2f (&PRE)[8], v2f (&PIM)[8],
                                         const float4* smat) {
    float4 m = smat[L * NQ + W];
    v2f bx = {m.x, m.x}, by = {m.y, m.y}, bz = {m.z, m.z}, bw = {m.w, m.w};
    #pragma unroll
    for (int j = 0; j < 8; j++) {
        if (j & (1 << Q)) continue;
        int j2 = j | (1 << Q);
        v2f re0 = PRE[j], im0 = PIM[j], re1 = PRE[j2], im1 = PIM[j2];
        PRE[j]  = __builtin_elementwise_fma(bx, re0,
                  __builtin_elementwise_fma(by, -im0,
                  __builtin_elementwise_fma(bz, re1, -bw * im1)));
        PIM[j]  = __builtin_elementwise_fma(bx, im0,
                  __builtin_elementwise_fma(by, re0,
                  __builtin_elementwise_fma(bz, im1, bw * re1)));
        PRE[j2] = __builtin_elementwise_fma(bx, re1,
                  __builtin_elementwise_fma(by, im1,
                  __builtin_elementwise_fma(bz, -re0, -bw * im0)));
        PIM[j2] = __builtin_elementwise_fma(bx, im1,
                  __builtin_elementwise_fma(by, -re1,
                  __builtin_elementwise_fma(bz, -im0, bw * re0)));
    }
}

template<int L>
__device__ __forceinline__ void do_layer(v2f (&PRE)[8], v2f (&PIM)[8],
                                         const float4* smat, float* lds, int tid) {
    if constexpr (L > 0)
        do_pass<1, L, 1>(PRE, PIM, lds, tid);
    reg_gate<L, 11, 0>(PRE, PIM, smat);
    reg_gate<L, 10, 1>(PRE, PIM, smat);
    reg_gate<L,  9, 2>(PRE, PIM, smat);
    do_pass<2, L, 0>(PRE, PIM, lds, tid);
    reg_gate<L, 8, 0>(PRE, PIM, smat);
    reg_gate<L, 7, 1>(PRE, PIM, smat);
    reg_gate<L, 6, 2>(PRE, PIM, smat);
    do_pass<3, L, 1>(PRE, PIM, lds, tid);
    reg_gate<L, 5, 0>(PRE, PIM, smat);
    reg_gate<L, 4, 1>(PRE, PIM, smat);
    reg_gate<L, 3, 2>(PRE, PIM, smat);
    do_pass<4, L, 0>(PRE, PIM, lds, tid);
    reg_gate<L, 2, 0>(PRE, PIM, smat);
    reg_gate<L, 1, 1>(PRE, PIM, smat);
    reg_gate<L, 0, 2>(PRE, PIM, smat);
}

__global__ __launch_bounds__(TPB) void qsim_kernel(
    const float* __restrict__ x,        // [512,12]
    const float* __restrict__ weights,  // [6,12,3]
    const float* __restrict__ Wp,       // [12]
    const float* __restrict__ bptr,     // [1]
    float* __restrict__ out)            // [512]
{
    __shared__ float  lds[2 * 2 * DIM]; // 64 KB: 2 buffers x (RE plane | IM plane)
    __shared__ float4 smat[NLAYERS * NQ];
    __shared__ float  scs[NQ], sss[NQ];
    __shared__ float  red[4];

    const int tid = threadIdx.x;
    const int b   = blockIdx.x;

    if (tid < NQ) {
        float s_, c_;
        sincosf(0.5f * x[b * NQ + tid], &s_, &c_);
        scs[tid] = c_; sss[tid] = s_;
    }
    if (tid < NLAYERS * NQ) {
        float phi   = weights[tid * 3 + 0];
        float theta = weights[tid * 3 + 1];
        float omega = weights[tid * 3 + 2];
        float st, ct; sincosf(0.5f * theta, &st, &ct);
        float sp, cp; sincosf(0.5f * (phi + omega), &sp, &cp);
        float sm, cm; sincosf(0.5f * (phi - omega), &sm, &cm);
        smat[tid] = make_float4(cp * ct, -sp * ct, -cm * st, -sm * st);
    }
    __syncthreads();

    // init, identity basis: k = (tid<<4)|l; k bit p <-> wire 11-p.
    // tid bit j <-> wire 7-j; local bits 0,1,2 <-> wires 11,10,9; bit3 <-> wire 8.
    float base = 1.0f;
    #pragma unroll
    for (int j = 0; j < 8; j++) {
        int w = 7 - j;
        base *= ((tid >> j) & 1) ? sss[w] : scs[w];
    }
    v2f PRE[8], PIM[8];
    float c8 = scs[8], s8 = sss[8];
    #pragma unroll
    for (int j = 0; j < 8; j++) {
        float a = base;
        #pragma unroll
        for (int p = 0; p < 3; p++) {
            int w = NQ - 1 - p;
            a *= ((j >> p) & 1) ? sss[w] : scs[w];
        }
        PRE[j].x = a * c8;  PRE[j].y = a * s8;
        PIM[j].x = 0.0f;    PIM[j].y = 0.0f;
    }

    do_layer<0>(PRE, PIM, smat, lds, tid);
    do_layer<1>(PRE, PIM, smat, lds, tid);
    do_layer<2>(PRE, PIM, smat, lds, tid);
    do_layer<3>(PRE, PIM, smat, lds, tid);
    do_layer<4>(PRE, PIM, smat, lds, tid);
    do_layer<5>(PRE, PIM, smat, lds, tid);

    // expectation: coef = b + sum_p W[11-p]*(1-2*bit_p(i(k))), packed halves
    const float bv = bptr[0];
    float wbT[NQ];
    #pragma unroll
    for (int p = 0; p < NQ; p++) {
        uint32_t row = CK.frow[p];
        int tp = __popc(tid & (int)(row >> 4)) & 1;
        float Wv = Wp[NQ - 1 - p];
        wbT[p] = tp ? -Wv : Wv;
    }
    v2f acc2 = {0.0f, 0.0f};
    #pragma unroll
    for (int j = 0; j < 8; j++) {
        float cx = bv, cy = bv;
        #pragma unroll
        for (int p = 0; p < NQ; p++) {
            uint32_t row = CK.frow[p];
            float s = (__popc(j & (int)(row & 7u)) & 1) ? -wbT[p] : wbT[p];
            cx += s;
            cy += (row & 8u) ? -s : s;
        }
        v2f c = {cx, cy};
        acc2 += (PRE[j] * PRE[j] + PIM[j] * PIM[j]) * c;
    }
    float acc = acc2.x + acc2.y;
    #pragma unroll
    for (int off = 32; off > 0; off >>= 1)
        acc += __shfl_down(acc, off, 64);
    if ((tid & 63) == 0) red[tid >> 6] = acc;
    __syncthreads();
    if (tid == 0) out[b] = red[0] + red[1] + red[2] + red[3];
}

extern "C" void kernel_launch(void* const* d_in, const int* in_sizes, int n_in,
                              void* d_out, int out_size, void* d_ws, size_t ws_size,
                              hipStream_t stream) {
    const float* x       = (const float*)d_in[0];
    const float* weights = (const float*)d_in[1];
    const float* W       = (const float*)d_in[2];
    const float* bptr    = (const float*)d_in[3];
    qsim_kernel<<<512, TPB, 0, stream>>>(x, weights, W, bptr, (float*)d_out);
}